// Round 2
// baseline (644.587 us; speedup 1.0000x reference)
//
#include <hip/hip_runtime.h>
#include <stdint.h>

// ResidualGraphConv: out[b] = concat(W1*[x,xA,xA^2,xA^3]+b1, relu(W2*[...]+b2))
// B=16, C=64, N=2048, deg+1=4, half=32.
//
// Pipeline:
//  1) relayout_adj: adj f32 [b][k][m] -> adjS bf16 subtiled [b][g=m/16][kb=k/8][j=m%16][r=k%8]
//     (B-operand-friendly: MFMA B frag = one ds_read_b128 per lane)
//  2) convert_x:    x f32 -> xp0 bf16 [b][c][n]
//  3) hop x3:       xp_d = xp_{d-1} @ adj   (bf16 MFMA 16x16x32, f32 accum)
//  4) proj:         out = concat(W1 . xps + b1, relu(W2 . xps + b2))  (f32 VALU)

typedef __attribute__((ext_vector_type(8))) __bf16 bf16x8;
typedef __attribute__((ext_vector_type(4))) float f32x4;

#define NB 16
#define NN 2048
#define NC 64
#define XPE (NB * NC * NN)          // elems per xp buffer = 2,097,152
#define ADJS_BYTES ((size_t)NB * NN * NN * 2)   // 134,217,728

static __device__ inline unsigned short f32_to_bf16(float f) {
  union { float f; unsigned int u; } v; v.f = f;
  unsigned int lsb = (v.u >> 16) & 1u;
  return (unsigned short)((v.u + 0x7fffu + lsb) >> 16);   // RNE
}
static __device__ inline float bf16_to_f32(unsigned short h) {
  union { unsigned int u; float f; } v; v.u = ((unsigned int)h) << 16;
  return v.f;
}

// ---------------------------------------------------------------------------
// 1) adj f32 [b][k][m] -> adjS bf16, element (k,m) at ((b*128+g)*256+kb)*128 + j*8 + r
//    g=m/16, j=m%16, kb=k/8, r=k%8.  One thread = one 16B output chunk (8 k's, fixed m).
__global__ __launch_bounds__(256) void relayout_adj(const float* __restrict__ adj,
                                                    unsigned short* __restrict__ adjS) {
  int id = blockIdx.x * 256 + threadIdx.x;       // 8,388,608 chunks total
  int j  = id & 15;
  int kb = (id >> 4) & 255;
  int g  = (id >> 12) & 127;
  int b  = id >> 19;
  const float* src = adj + ((size_t)(b * NN + kb * 8)) * NN + g * 16 + j;
  unsigned int p[4];
  #pragma unroll
  for (int h = 0; h < 4; ++h) {
    unsigned short lo = f32_to_bf16(src[(size_t)(2 * h) * NN]);
    unsigned short hi = f32_to_bf16(src[(size_t)(2 * h + 1) * NN]);
    p[h] = (unsigned int)lo | ((unsigned int)hi << 16);
  }
  uint4* dst = (uint4*)(adjS + (size_t)id * 8);
  *dst = make_uint4(p[0], p[1], p[2], p[3]);
}

// ---------------------------------------------------------------------------
// 2) x f32 -> bf16, 8 elems/thread
__global__ __launch_bounds__(256) void convert_x(const float* __restrict__ x,
                                                 unsigned short* __restrict__ xp0) {
  int id = blockIdx.x * 256 + threadIdx.x;
  const float* s = x + (size_t)id * 8;
  unsigned int p[4];
  #pragma unroll
  for (int h = 0; h < 4; ++h) {
    unsigned short lo = f32_to_bf16(s[2 * h]);
    unsigned short hi = f32_to_bf16(s[2 * h + 1]);
    p[h] = (unsigned int)lo | ((unsigned int)hi << 16);
  }
  *(uint4*)(xp0 + (size_t)id * 8) = make_uint4(p[0], p[1], p[2], p[3]);
}

// ---------------------------------------------------------------------------
// 3) hop: Xout[b][c][m] = sum_n Z[b][c][n] * adj[b][n][m]  (bf16 in, bf16 out, f32 acc)
//    Block = (b, m-tile of 128). 4 waves, each 64x32 output. BK=64, 32 K-iters.
__global__ __launch_bounds__(256) void hop_kernel(const unsigned short* __restrict__ Z,
                                                  const unsigned short* __restrict__ adjS,
                                                  unsigned short* __restrict__ Xout) {
  int bx = blockIdx.x;
  int b = bx >> 4, mt = bx & 15;
  int tid = threadIdx.x;
  int w = tid >> 6, l = tid & 63;
  int l15 = l & 15, l4 = l >> 4;

  __shared__ unsigned short At[8192];      // [gl][kbl][j][r] = [8][8][16][8], 16 KB
  __shared__ unsigned short Zt[64 * 72];   // [c][k] padded +8 bf16/row, 9 KB

  f32x4 acc[4][2] = {};

  const unsigned short* adjB = adjS + ((size_t)(b * 128 + mt * 8)) * 256 * 128;
  const unsigned short* Zb   = Z + (size_t)b * NC * NN;

  for (int it = 0; it < 32; ++it) {
    int kb0 = it * 8;
    // stage adj tile: 1024 chunks of 16B, linear in both global and LDS
    #pragma unroll
    for (int q = 0; q < 4; ++q) {
      int ci = q * 256 + tid;
      int gl = ci >> 7;
      int rem = ci & 127;                  // kbl*16 + j
      int kbl = rem >> 4, j = rem & 15;
      uint4 v = *(const uint4*)(adjB + ((size_t)gl * 256 + kb0 + kbl) * 128 + j * 8);
      *(uint4*)&At[ci * 8] = v;
    }
    // stage Z tile [64][64] -> padded rows of 72
    #pragma unroll
    for (int p = 0; p < 2; ++p) {
      int ci = p * 256 + tid;
      int c = ci >> 3, seg = ci & 7;
      uint4 v = *(const uint4*)(Zb + c * NN + it * 64 + seg * 8);
      *(uint4*)&Zt[c * 72 + seg * 8] = v;
    }
    __syncthreads();

    #pragma unroll
    for (int kf = 0; kf < 2; ++kf) {
      bf16x8 az[4], bA[2];
      #pragma unroll
      for (int mi = 0; mi < 4; ++mi)
        az[mi] = *(const bf16x8*)&Zt[(mi * 16 + l15) * 72 + kf * 32 + l4 * 8];
      #pragma unroll
      for (int nj = 0; nj < 2; ++nj) {
        int gl = w * 2 + nj;
        bA[nj] = *(const bf16x8*)&At[((gl * 8 + 4 * kf + l4) * 16 + l15) * 8];
      }
      #pragma unroll
      for (int mi = 0; mi < 4; ++mi)
        #pragma unroll
        for (int nj = 0; nj < 2; ++nj)
          acc[mi][nj] = __builtin_amdgcn_mfma_f32_16x16x32_bf16(az[mi], bA[nj], acc[mi][nj], 0, 0, 0);
    }
    __syncthreads();
  }

  // epilogue: D layout col=lane&15, row=(lane>>4)*4+reg (guide-verified)
  unsigned short* outB = Xout + (size_t)b * NC * NN + mt * 128;
  #pragma unroll
  for (int mi = 0; mi < 4; ++mi)
    #pragma unroll
    for (int nj = 0; nj < 2; ++nj) {
      int col = w * 32 + nj * 16 + l15;
      #pragma unroll
      for (int r = 0; r < 4; ++r) {
        int row = mi * 16 + l4 * 4 + r;
        outB[row * NN + col] = f32_to_bf16(acc[mi][nj][r]);
      }
    }
}

// ---------------------------------------------------------------------------
// 4) projection: block = (b, n-tile of 256, arm). One thread = one n column.
__global__ __launch_bounds__(256) void proj_kernel(const unsigned short* __restrict__ xpb,
                                                   const float* __restrict__ W1,
                                                   const float* __restrict__ b1,
                                                   const float* __restrict__ W2,
                                                   const float* __restrict__ b2,
                                                   float* __restrict__ out) {
  int bx = blockIdx.x;
  int arm = bx & 1, nt = (bx >> 1) & 7, b = bx >> 4;
  int tid = threadIdx.x;
  const float* W    = arm ? W2 : W1;     // [4][32][64]
  const float* bias = arm ? b2 : b1;

  __shared__ float Wt[4][64][32];        // transposed: [d][c][o], 32 KB
  __shared__ float bl[32];
  {
    int o = tid & 31, c0 = tid >> 5;     // c0 in 0..7
    #pragma unroll
    for (int d = 0; d < 4; ++d) {
      const float* src = W + (d * 32 + o) * 64 + c0 * 8;
      float4 v0 = *(const float4*)src;
      float4 v1 = *(const float4*)(src + 4);
      Wt[d][c0 * 8 + 0][o] = v0.x; Wt[d][c0 * 8 + 1][o] = v0.y;
      Wt[d][c0 * 8 + 2][o] = v0.z; Wt[d][c0 * 8 + 3][o] = v0.w;
      Wt[d][c0 * 8 + 4][o] = v1.x; Wt[d][c0 * 8 + 5][o] = v1.y;
      Wt[d][c0 * 8 + 6][o] = v1.z; Wt[d][c0 * 8 + 7][o] = v1.w;
    }
    if (tid < 32) bl[tid] = bias[tid];
  }
  __syncthreads();

  int n = nt * 256 + tid;
  float4 acc[8] = {};
  #pragma unroll
  for (int d = 0; d < 4; ++d) {
    const unsigned short* xp = xpb + (size_t)d * XPE + (size_t)b * NC * NN + n;
    for (int c = 0; c < 64; ++c) {
      float v = bf16_to_f32(xp[c * NN]);
      #pragma unroll
      for (int o4 = 0; o4 < 8; ++o4) {
        float4 wv = *(const float4*)&Wt[d][c][o4 * 4];
        acc[o4].x = fmaf(wv.x, v, acc[o4].x);
        acc[o4].y = fmaf(wv.y, v, acc[o4].y);
        acc[o4].z = fmaf(wv.z, v, acc[o4].z);
        acc[o4].w = fmaf(wv.w, v, acc[o4].w);
      }
    }
  }
  float* ob = out + ((size_t)(b * 64 + arm * 32)) * NN + n;
  #pragma unroll
  for (int o4 = 0; o4 < 8; ++o4) {
    float rr[4] = {acc[o4].x, acc[o4].y, acc[o4].z, acc[o4].w};
    #pragma unroll
    for (int cc = 0; cc < 4; ++cc) {
      int o = o4 * 4 + cc;
      float r = rr[cc] + bl[o];
      if (arm) r = fmaxf(r, 0.f);
      ob[(size_t)o * NN] = r;
    }
  }
}

// ---------------------------------------------------------------------------
extern "C" void kernel_launch(void* const* d_in, const int* in_sizes, int n_in,
                              void* d_out, int out_size, void* d_ws, size_t ws_size,
                              hipStream_t stream) {
  const float* adj = (const float*)d_in[0];
  const float* x   = (const float*)d_in[1];
  const float* W1  = (const float*)d_in[2];
  const float* b1  = (const float*)d_in[3];
  const float* W2  = (const float*)d_in[4];
  const float* b2  = (const float*)d_in[5];
  float* out = (float*)d_out;

  unsigned short* adjS = (unsigned short*)d_ws;                       // 134 MB
  unsigned short* xpb  = (unsigned short*)((char*)d_ws + ADJS_BYTES); // 4 x 4 MB
  // total ws need = 150,994,944 bytes

  hipLaunchKernelGGL(relayout_adj, dim3(32768), dim3(256), 0, stream, adj, adjS);
  hipLaunchKernelGGL(convert_x,   dim3(1024),  dim3(256), 0, stream, x, xpb);
  hipLaunchKernelGGL(hop_kernel,  dim3(256),   dim3(256), 0, stream, xpb,            adjS, xpb + XPE);
  hipLaunchKernelGGL(hop_kernel,  dim3(256),   dim3(256), 0, stream, xpb + XPE,      adjS, xpb + 2 * XPE);
  hipLaunchKernelGGL(hop_kernel,  dim3(256),   dim3(256), 0, stream, xpb + 2 * XPE,  adjS, xpb + 3 * XPE);
  hipLaunchKernelGGL(proj_kernel, dim3(256),   dim3(256), 0, stream, xpb, W1, b1, W2, b2, out);
}